// Round 5
// baseline (288.675 us; speedup 1.0000x reference)
//
#include <hip/hip_runtime.h>
#include <stdint.h>
#include <stddef.h>

// AttentionLayer2D: B=4, N=64*64=4096, C=512, Cfg=64
// out = gamma * softmax(g @ f^T) @ h + x   (per batch), residual in fp32.

#define LOG2E 1.44269504088896f

typedef float f32x4 __attribute__((ext_vector_type(4)));
typedef short s16x8 __attribute__((ext_vector_type(8)));
typedef unsigned u32x2 __attribute__((ext_vector_type(2)));

__device__ __forceinline__ unsigned short f2bf(float f) {
  unsigned u = __builtin_bit_cast(unsigned, f);
  u += 0x7FFFu + ((u >> 16) & 1u);   // RNE
  return (unsigned short)(u >> 16);
}

__device__ __forceinline__ unsigned cvt_pk_bf16(float lo, float hi) {
  unsigned r;
  asm("v_cvt_pk_bf16_f32 %0, %1, %2" : "=v"(r) : "v"(lo), "v"(hi));
  return r;
}

// ---------- weight transpose + bf16 convert: wT[n][k], n in [0,640), k in [0,512)
__global__ void wt_kernel(const float* __restrict__ kf, const float* __restrict__ kg,
                          const float* __restrict__ kh, unsigned short* __restrict__ wT) {
  const int n = blockIdx.x;
  const float* src; int stride; float scl = 1.0f;
  if (n < 64)       { src = kf + n;         stride = 64;  }
  else if (n < 128) { src = kg + (n - 64);  stride = 64;  scl = LOG2E; }
  else              { src = kh + (n - 128); stride = 512; }
  for (int k = threadIdx.x; k < 512; k += blockDim.x)
    wT[(size_t)n * 512 + k] = f2bf(src[(size_t)k * stride] * scl);
}

// ---------- projection GEMM: x[16384x512] @ wT^T -> f,g (bf16 [row][64]) and
// hP panels: hP[b][j>>5][c][j&31] (each 512x32 panel contiguous, 32KB).
// grid (256 m-tiles, 2 n-groups of 5 panels); block 256 thr = 4 waves, 64 rows.
__global__ __launch_bounds__(256) void gemm_kernel(
    const float* __restrict__ x, const unsigned short* __restrict__ wT,
    const float* __restrict__ bfv, const float* __restrict__ bgv, const float* __restrict__ bhv,
    unsigned short* __restrict__ fO, unsigned short* __restrict__ gO,
    unsigned short* __restrict__ hP)
{
  __shared__ __align__(16) unsigned short tile[64 * 64];   // 8 KB
  const int tid = threadIdx.x;
  const int w = tid >> 6, l = tid & 63;
  const int l15 = l & 15, sub = l >> 4;
  const int mb = blockIdx.x;
  const int ng = blockIdx.y;            // n-group: panels ng*5 .. ng*5+4
  const int bb = mb >> 6;
  const int qb = (mb * 64) & 4095;

  // A fragments straight from HBM (16 rows x 128B per instr, 16 segments)
  const float* xrow = x + (size_t)(mb * 64 + w * 16 + l15) * 512;
  s16x8 afr[16];
#pragma unroll
  for (int kk = 0; kk < 16; ++kk) {
    const f32x4 a0 = *(const f32x4*)(xrow + kk * 32 + sub * 8);
    const f32x4 a1 = *(const f32x4*)(xrow + kk * 32 + sub * 8 + 4);
    s16x8 af;
    af[0] = (short)f2bf(a0[0]); af[1] = (short)f2bf(a0[1]);
    af[2] = (short)f2bf(a0[2]); af[3] = (short)f2bf(a0[3]);
    af[4] = (short)f2bf(a1[0]); af[5] = (short)f2bf(a1[1]);
    af[6] = (short)f2bf(a1[2]); af[7] = (short)f2bf(a1[3]);
    afr[kk] = af;
  }

  for (int nbl = 0; nbl < 5; ++nbl) {
    const int nb = ng * 5 + nbl;
    f32x4 acc[4] = {{0,0,0,0},{0,0,0,0},{0,0,0,0},{0,0,0,0}};
#pragma unroll
    for (int ks = 0; ks < 16; ++ks) {
#pragma unroll
      for (int t = 0; t < 4; ++t) {
        const s16x8 bfr = *(const s16x8*)(wT + (size_t)(nb * 64 + 16 * t + l15) * 512
                                              + ks * 32 + sub * 8);
        acc[t] = __builtin_amdgcn_mfma_f32_16x16x32_bf16(afr[ks], bfr, acc[t], 0, 0, 0);
      }
    }
    __syncthreads();   // previous tile fully read
#pragma unroll
    for (int t = 0; t < 4; ++t) {
      const int n = nb * 64 + 16 * t + l15;
      const float bv = (n < 64) ? bfv[n] : (n < 128 ? bgv[n - 64] * LOG2E : bhv[n - 128]);
#pragma unroll
      for (int v = 0; v < 4; ++v) {
        const int r = w * 16 + 4 * sub + v;
        const int c = 16 * t + l15;
        const unsigned short val = f2bf(acc[t][v] + bv);
        if (nb <= 1) tile[r * 64 + c] = val;   // f/g: [row][chan]
        else         tile[c * 64 + r] = val;   // h:   [chan][j]
      }
    }
    __syncthreads();
#pragma unroll
    for (int it = 0; it < 2; ++it) {
      const int u = tid + it * 256;
      const int rr = u >> 3, chh = u & 7;
      const s16x8 vdat = *(const s16x8*)&tile[rr * 64 + chh * 8];
      if (nb == 0)      *(s16x8*)(fO + (size_t)(mb * 64 + rr) * 64 + chh * 8) = vdat;
      else if (nb == 1) *(s16x8*)(gO + (size_t)(mb * 64 + rr) * 64 + chh * 8) = vdat;
      else {
        const int j8 = qb + chh * 8;
        *(s16x8*)(hP + (((size_t)bb * 128 + (j8 >> 5)) * 512 + (nb * 64 - 128 + rr)) * 32
                      + (j8 & 31)) = vdat;
      }
    }
  }
}

// ---------- flash attention: block = 32 q-rows, 8 waves = 2 j-streams x 4 waves.
// Stream s: panels [64s, 64s+64). Within stream: waves 0,1 own q-tiles 0,1 (QK^T+softmax);
// all 4 waves do PV on c-slice [128*ws, 128*ws+128). h/f direct from L2; P via padded LDS.
__global__ __launch_bounds__(512, 4) void attn_kernel(
    const unsigned short* __restrict__ fM, const unsigned short* __restrict__ gM,
    const unsigned short* __restrict__ hP, const float* __restrict__ x,
    const float* __restrict__ gamma, float* __restrict__ out)
{
  __shared__ __align__(16) char smem[66048];   // main: pbuf[2][32*20 u32] + scl; epi: 2x[16][516] f32
  __shared__ float mfin[2][32];
  __shared__ float lfin[2][32];
  unsigned* pbuf = (unsigned*)smem;            // stream s at u32 offset s*640 (pad: 20 u32/row)
  float* sclp    = (float*)(smem + 5120);      // [2][32]

  const int tid = threadIdx.x;
  const int w = tid >> 6, l = tid & 63;
  const int l15 = l & 15, sub = l >> 4;
  const int s = w >> 2, ws = w & 3;

  // bijective XCD swizzle: 512 blocks -> XCD k gets logical [64k, 64k+64)
  const int p = blockIdx.x;
  const int L = (p & 7) * 64 + (p >> 3);
  const int b = L >> 7;
  const int qbase = (L & 127) * 32;

  const unsigned short* fMb = fM + (size_t)b * 4096 * 64;
  const unsigned short* hPb = hP + (size_t)b * 128 * 16384;
  const unsigned short* hlane = hPb + (size_t)(ws * 128 + l15) * 32 + sub * 8;
  unsigned* pb = pbuf + s * 640;
  float* sc_arr = sclp + s * 32;
  const int qown = ws * 16 + l15;              // valid for owner waves (ws<2)
  const bool owner = (ws < 2);

  s16x8 ga0 = {}, ga1 = {};
  if (owner) {
    const unsigned short* grow = gM + ((size_t)b * 4096 + qbase + qown) * 64;
    ga0 = *(const s16x8*)(grow + 8 * sub);
    ga1 = *(const s16x8*)(grow + 32 + 8 * sub);
  }

  float mrun = -1e30f, lsum = 0.f;
  f32x4 o[8][2];
#pragma unroll
  for (int ct = 0; ct < 8; ++ct) { o[ct][0] = (f32x4){0,0,0,0}; o[ct][1] = (f32x4){0,0,0,0}; }

  for (int it = 0; it < 64; ++it) {
    const int jb = s * 64 + it;
    const unsigned short* hp = hlane + (size_t)jb * 16384;
    s16x8 h03[4];
#pragma unroll
    for (int ct = 0; ct < 4; ++ct) h03[ct] = *(const s16x8*)(hp + ct * 512);

    if (owner) {
      const unsigned short* fp = fMb + (size_t)(jb * 32 + l15) * 64 + 8 * sub;
      const s16x8 fr00 = *(const s16x8*)(fp);
      const s16x8 fr01 = *(const s16x8*)(fp + 32);
      const s16x8 fr10 = *(const s16x8*)(fp + 1024);
      const s16x8 fr11 = *(const s16x8*)(fp + 1024 + 32);
      f32x4 st0 = {0,0,0,0}, st1 = {0,0,0,0};
      st0 = __builtin_amdgcn_mfma_f32_16x16x32_bf16(fr00, ga0, st0, 0, 0, 0);
      st0 = __builtin_amdgcn_mfma_f32_16x16x32_bf16(fr01, ga1, st0, 0, 0, 0);
      st1 = __builtin_amdgcn_mfma_f32_16x16x32_bf16(fr10, ga0, st1, 0, 0, 0);
      st1 = __builtin_amdgcn_mfma_f32_16x16x32_bf16(fr11, ga1, st1, 0, 0, 0);
      // lane: st0[v]=S'[4sub+v][q=l15], st1[v]=S'[16+4sub+v][q=l15] (log2 domain)

      float tmx = fmaxf(fmaxf(fmaxf(st0[0], st0[1]), fmaxf(st0[2], st0[3])),
                        fmaxf(fmaxf(st1[0], st1[1]), fmaxf(st1[2], st1[3])));
      tmx = fmaxf(tmx, __shfl_xor(tmx, 16));
      tmx = fmaxf(tmx, __shfl_xor(tmx, 32));
      float sc = 1.0f;
      if (__any(tmx > mrun + 8.0f)) {          // defer-max, THR=8
        const float mn = fmaxf(mrun, tmx);
        sc = __builtin_amdgcn_exp2f(mrun - mn);
        mrun = mn; lsum *= sc;
      }
      float p0[4], p1[4];
#pragma unroll
      for (int v = 0; v < 4; ++v) {
        p0[v] = __builtin_amdgcn_exp2f(st0[v] - mrun);
        p1[v] = __builtin_amdgcn_exp2f(st1[v] - mrun);
      }
      float rs = (p0[0] + p0[1]) + (p0[2] + p0[3]) + (p1[0] + p1[1]) + (p1[2] + p1[3]);
      rs += __shfl_xor(rs, 16);
      rs += __shfl_xor(rs, 32);
      lsum += rs;

      const unsigned pk0 = cvt_pk_bf16(p0[0], p0[1]);
      const unsigned pk1 = cvt_pk_bf16(p0[2], p0[3]);
      const unsigned pk2 = cvt_pk_bf16(p1[0], p1[1]);
      const unsigned pk3 = cvt_pk_bf16(p1[2], p1[3]);
      *(u32x2*)&pb[qown * 20 + 2 * sub]     = (u32x2){pk0, pk1};
      *(u32x2*)&pb[qown * 20 + 8 + 2 * sub] = (u32x2){pk2, pk3};
      if (sub == 0) sc_arr[qown] = sc;
    }
    s16x8 h47[4];
#pragma unroll
    for (int ct = 0; ct < 4; ++ct) h47[ct] = *(const s16x8*)(hp + (4 + ct) * 512);
    __syncthreads();                           // P + scl ready

    // PV: rescale (rare) + 8 c-tiles x 2 q-tiles
    float sc2[2] = {sc_arr[l15], sc_arr[16 + l15]};
    if (__any(fminf(sc2[0], sc2[1]) < 1.0f)) {
#pragma unroll
      for (int ct = 0; ct < 8; ++ct) { o[ct][0] *= sc2[0]; o[ct][1] *= sc2[1]; }
    }
    const s16x8 pa0 = *(const s16x8*)((const unsigned short*)pb + l15 * 40 + sub * 8);
    const s16x8 pa1 = *(const s16x8*)((const unsigned short*)pb + (16 + l15) * 40 + sub * 8);
    __builtin_amdgcn_s_setprio(1);
#pragma unroll
    for (int ct = 0; ct < 4; ++ct) {
      o[ct][0] = __builtin_amdgcn_mfma_f32_16x16x32_bf16(h03[ct], pa0, o[ct][0], 0, 0, 0);
      o[ct][1] = __builtin_amdgcn_mfma_f32_16x16x32_bf16(h03[ct], pa1, o[ct][1], 0, 0, 0);
    }
#pragma unroll
    for (int ct = 0; ct < 4; ++ct) {
      o[4 + ct][0] = __builtin_amdgcn_mfma_f32_16x16x32_bf16(h47[ct], pa0, o[4 + ct][0], 0, 0, 0);
      o[4 + ct][1] = __builtin_amdgcn_mfma_f32_16x16x32_bf16(h47[ct], pa1, o[4 + ct][1], 0, 0, 0);
    }
    __builtin_amdgcn_s_setprio(0);
    __syncthreads();                           // pbuf reads done before next write
  }

  // ---- merge the two streams + epilogue
  if (owner && sub == 0) { mfin[s][qown] = mrun; lfin[s][qown] = lsum; }
  __syncthreads();
  const float gam = gamma[0];
  float* oldsS = (float*)(smem + s * 33024);   // per-stream [16][516] f32
  const float* oA = (const float*)smem;
  const float* oB = (const float*)(smem + 33024);
#pragma unroll
  for (int qt = 0; qt < 2; ++qt) {
    const int q = qt * 16 + l15;
    const float mA = mfin[0][q], mB = mfin[1][q];
    const float mm = fmaxf(mA, mB);
    const float eA = __builtin_amdgcn_exp2f(mA - mm);
    const float eB = __builtin_amdgcn_exp2f(mB - mm);
    const float Lt = lfin[0][q] * eA + lfin[1][q] * eB;
    const float fac = gam * ((s == 0) ? eA : eB) / Lt;
#pragma unroll
    for (int ct = 0; ct < 8; ++ct) {
      const f32x4 vv = o[ct][qt] * fac;
      *(f32x4*)&oldsS[l15 * 516 + ws * 128 + ct * 16 + 4 * sub] = vv;
    }
    __syncthreads();
    const int r = tid >> 5, c0 = (tid & 31) * 16;
    const float* xr  = x   + ((size_t)b * 4096 + qbase + qt * 16 + r) * 512;
    float*       orw = out + ((size_t)b * 4096 + qbase + qt * 16 + r) * 512;
#pragma unroll
    for (int i = 0; i < 4; ++i) {
      const int cc = c0 + i * 4;
      const f32x4 va = *(const f32x4*)&oA[r * 516 + cc];
      const f32x4 vb = *(const f32x4*)&oB[r * 516 + cc];
      const f32x4 xv = *(const f32x4*)(xr + cc);
      *(f32x4*)(orw + cc) = va + vb + xv;
    }
    __syncthreads();
  }
}

extern "C" void kernel_launch(void* const* d_in, const int* in_sizes, int n_in,
                              void* d_out, int out_size, void* d_ws, size_t ws_size,
                              hipStream_t stream) {
  const float* x     = (const float*)d_in[0];
  const float* kf    = (const float*)d_in[1];
  const float* kg    = (const float*)d_in[2];
  const float* kh    = (const float*)d_in[3];
  const float* bf    = (const float*)d_in[4];
  const float* bg    = (const float*)d_in[5];
  const float* bh    = (const float*)d_in[6];
  const float* gamma = (const float*)d_in[7];
  float* out = (float*)d_out;

  char* ws = (char*)d_ws;
  unsigned short* fO = (unsigned short*)(ws);
  unsigned short* gO = (unsigned short*)(ws + (2u << 20));
  unsigned short* hP = (unsigned short*)(ws + (4u << 20));
  unsigned short* wT = (unsigned short*)(ws + (20u << 20));

  hipLaunchKernelGGL(wt_kernel,   dim3(640),     dim3(256), 0, stream, kf, kg, kh, wT);
  hipLaunchKernelGGL(gemm_kernel, dim3(256, 2),  dim3(256), 0, stream,
                     x, wT, bf, bg, bh, fO, gO, hP);
  hipLaunchKernelGGL(attn_kernel, dim3(512),     dim3(512), 0, stream,
                     fO, gO, hP, x, gamma, out);
}

// Round 6
// 247.880 us; speedup vs baseline: 1.1646x; 1.1646x over previous
//
#include <hip/hip_runtime.h>
#include <stdint.h>
#include <stddef.h>

// AttentionLayer2D: B=4, N=64*64=4096, C=512, Cfg=64
// out = gamma * softmax(g @ f^T) @ h + x   (per batch), residual in fp32.

#define LOG2E 1.44269504088896f

typedef float f32x4 __attribute__((ext_vector_type(4)));
typedef short s16x8 __attribute__((ext_vector_type(8)));
typedef unsigned u32x2 __attribute__((ext_vector_type(2)));

__device__ __forceinline__ unsigned short f2bf(float f) {
  unsigned u = __builtin_bit_cast(unsigned, f);
  u += 0x7FFFu + ((u >> 16) & 1u);   // RNE
  return (unsigned short)(u >> 16);
}

__device__ __forceinline__ unsigned cvt_pk_bf16(float lo, float hi) {
  unsigned r;
  asm("v_cvt_pk_bf16_f32 %0, %1, %2" : "=v"(r) : "v"(lo), "v"(hi));
  return r;
}

// ---------- weight transpose (coalesced): wT[n][k] bf16, n<640, k<512.
// n-tile 0 = kernel_f, 1 = kernel_g (x log2e), 2..9 = kernel_h cols.
// Block (nt, kt): read 128 k-rows x 64 cols coalesced -> LDS -> write 64 n x 128 k.
__global__ __launch_bounds__(256) void wt_kernel(
    const float* __restrict__ kf, const float* __restrict__ kg,
    const float* __restrict__ kh, unsigned short* __restrict__ wT) {
  __shared__ float lds[128 * 68];
  const int nt = blockIdx.x, kt = blockIdx.y;
  const int tid = threadIdx.x;
  const int n0 = nt * 64, k0 = kt * 128;
  const float* src; int stride; int c0; float scl = 1.0f;
  if (nt == 0)      { src = kf; stride = 64;  c0 = 0; }
  else if (nt == 1) { src = kg; stride = 64;  c0 = 0; scl = LOG2E; }
  else              { src = kh; stride = 512; c0 = (nt - 2) * 64; }
#pragma unroll
  for (int r = 0; r < 8; ++r) {
    const int lin = r * 256 + tid;
    const int row = lin >> 4, col4 = (lin & 15) * 4;
    const f32x4 v = *(const f32x4*)(src + (size_t)(k0 + row) * stride + c0 + col4);
    *(f32x4*)&lds[row * 68 + col4] = v;
  }
  __syncthreads();
  const int nl = tid >> 2, ks = tid & 3;
#pragma unroll
  for (int seg = 0; seg < 4; ++seg) {
    s16x8 v;
#pragma unroll
    for (int e = 0; e < 8; ++e)
      v[e] = (short)f2bf(lds[(ks * 32 + seg * 8 + e) * 68 + nl] * scl);
    *(s16x8*)(wT + (size_t)(n0 + nl) * 512 + k0 + ks * 32 + seg * 8) = v;
  }
}

// ---------- projection GEMM: x[16384x512] @ wT^T -> f,g (bf16 [row][64]) and
// hP panels: hP[b][j>>5][c][j&31] (each 512x32 panel contiguous, 32KB).
// grid (256 m-tiles, 2 n-groups of 5 panels); block 256 thr = 4 waves, 64 rows.
__global__ __launch_bounds__(256) void gemm_kernel(
    const float* __restrict__ x, const unsigned short* __restrict__ wT,
    const float* __restrict__ bfv, const float* __restrict__ bgv, const float* __restrict__ bhv,
    unsigned short* __restrict__ fO, unsigned short* __restrict__ gO,
    unsigned short* __restrict__ hP)
{
  __shared__ __align__(16) unsigned short tile[64 * 64];   // 8 KB
  const int tid = threadIdx.x;
  const int w = tid >> 6, l = tid & 63;
  const int l15 = l & 15, sub = l >> 4;
  const int mb = blockIdx.x;
  const int ng = blockIdx.y;            // n-group: panels ng*5 .. ng*5+4
  const int bb = mb >> 6;
  const int qb = (mb * 64) & 4095;

  // A fragments straight from HBM (16 rows x 128B per instr, 16 segments)
  const float* xrow = x + (size_t)(mb * 64 + w * 16 + l15) * 512;
  s16x8 afr[16];
#pragma unroll
  for (int kk = 0; kk < 16; ++kk) {
    const f32x4 a0 = *(const f32x4*)(xrow + kk * 32 + sub * 8);
    const f32x4 a1 = *(const f32x4*)(xrow + kk * 32 + sub * 8 + 4);
    s16x8 af;
    af[0] = (short)f2bf(a0[0]); af[1] = (short)f2bf(a0[1]);
    af[2] = (short)f2bf(a0[2]); af[3] = (short)f2bf(a0[3]);
    af[4] = (short)f2bf(a1[0]); af[5] = (short)f2bf(a1[1]);
    af[6] = (short)f2bf(a1[2]); af[7] = (short)f2bf(a1[3]);
    afr[kk] = af;
  }

  for (int nbl = 0; nbl < 5; ++nbl) {
    const int nb = ng * 5 + nbl;
    f32x4 acc[4] = {{0,0,0,0},{0,0,0,0},{0,0,0,0},{0,0,0,0}};
#pragma unroll
    for (int ks = 0; ks < 16; ++ks) {
#pragma unroll
      for (int t = 0; t < 4; ++t) {
        const s16x8 bfr = *(const s16x8*)(wT + (size_t)(nb * 64 + 16 * t + l15) * 512
                                              + ks * 32 + sub * 8);
        acc[t] = __builtin_amdgcn_mfma_f32_16x16x32_bf16(afr[ks], bfr, acc[t], 0, 0, 0);
      }
    }
    __syncthreads();   // previous tile fully read
#pragma unroll
    for (int t = 0; t < 4; ++t) {
      const int n = nb * 64 + 16 * t + l15;
      const float bv = (n < 64) ? bfv[n] : (n < 128 ? bgv[n - 64] * LOG2E : bhv[n - 128]);
#pragma unroll
      for (int v = 0; v < 4; ++v) {
        const int r = w * 16 + 4 * sub + v;
        const int c = 16 * t + l15;
        const unsigned short val = f2bf(acc[t][v] + bv);
        if (nb <= 1) tile[r * 64 + c] = val;   // f/g: [row][chan]
        else         tile[c * 64 + r] = val;   // h:   [chan][j]
      }
    }
    __syncthreads();
#pragma unroll
    for (int it = 0; it < 2; ++it) {
      const int u = tid + it * 256;
      const int rr = u >> 3, chh = u & 7;
      const s16x8 vdat = *(const s16x8*)&tile[rr * 64 + chh * 8];
      if (nb == 0)      *(s16x8*)(fO + (size_t)(mb * 64 + rr) * 64 + chh * 8) = vdat;
      else if (nb == 1) *(s16x8*)(gO + (size_t)(mb * 64 + rr) * 64 + chh * 8) = vdat;
      else {
        const int j8 = qb + chh * 8;
        *(s16x8*)(hP + (((size_t)bb * 128 + (j8 >> 5)) * 512 + (nb * 64 - 128 + rr)) * 32
                      + (j8 & 31)) = vdat;
      }
    }
  }
}

// ---------- flash attention: block = 64 q-rows, 8 waves = 2 j-streams x 4 waves.
// Stream s: panels [64s, 64s+64). Wave ws: q-tile ws (QK^T+softmax) AND c-slice
// [128*ws,128*ws+128) (PV). h/f direct from L2; P double-buffered in padded LDS;
// h double-buffered in registers one full iteration ahead; ONE barrier per iter.
__global__ __launch_bounds__(512, 2) void attn_kernel(
    const unsigned short* __restrict__ fM, const unsigned short* __restrict__ gM,
    const unsigned short* __restrict__ hP, const float* __restrict__ x,
    const float* __restrict__ gamma, float* __restrict__ out)
{
  // main: pbuf [2 stream][2 parity][64*20 u32] = 20480B, scl [2][2][64] f32 = 2048B
  // epilogue overlays: 2 x [16][516] f32 (oA at 0, oB at 33024)
  __shared__ __align__(16) char smem[66048];
  __shared__ float mfin[2][64];
  __shared__ float lfin[2][64];
  unsigned* pbuf = (unsigned*)smem;
  float* sclp    = (float*)(smem + 20480);

  const int tid = threadIdx.x;
  const int w = tid >> 6, l = tid & 63;
  const int l15 = l & 15, sub = l >> 4;
  const int s = w >> 2, ws = w & 3;

  // bijective XCD swizzle: 256 blocks -> XCD k gets logical [32k, 32k+32)
  const int p = blockIdx.x;
  const int L = (p & 7) * 32 + (p >> 3);
  const int b = L >> 6;
  const int qbase = (L & 63) * 64;

  const unsigned short* fMb = fM + (size_t)b * 4096 * 64;
  const unsigned short* hPb = hP + (size_t)b * 128 * 16384;
  const unsigned short* hlane = hPb + (size_t)(ws * 128 + l15) * 32 + sub * 8;
  unsigned* pbS = pbuf + s * 2560;          // [2 parity][1280]
  float* scS    = sclp + s * 128;           // [2 parity][64]
  const int qown = ws * 16 + l15;

  const unsigned short* grow = gM + ((size_t)b * 4096 + qbase + qown) * 64;
  const s16x8 ga0 = *(const s16x8*)(grow + 8 * sub);
  const s16x8 ga1 = *(const s16x8*)(grow + 32 + 8 * sub);

  float mrun = -1e30f, lsum = 0.f;
  f32x4 o[8][4];
#pragma unroll
  for (int ct = 0; ct < 8; ++ct)
#pragma unroll
    for (int qt = 0; qt < 4; ++qt) o[ct][qt] = (f32x4){0, 0, 0, 0};

  // prologue: h(0) and f(0)
  s16x8 hA[8], hB[8];
  {
    const unsigned short* hp = hlane + (size_t)(s * 64) * 16384;
#pragma unroll
    for (int ct = 0; ct < 8; ++ct) hA[ct] = *(const s16x8*)(hp + ct * 512);
  }
  const unsigned short* f0p = fMb + (size_t)(s * 64 * 32 + l15) * 64 + 8 * sub;
  s16x8 fr00 = *(const s16x8*)(f0p);
  s16x8 fr01 = *(const s16x8*)(f0p + 32);
  s16x8 fr10 = *(const s16x8*)(f0p + 1024);
  s16x8 fr11 = *(const s16x8*)(f0p + 1024 + 32);

#define ATTN_BODY(IT, HCUR, HNXT, PAR)                                              \
  {                                                                                 \
    const int jb = s * 64 + (IT);                                                   \
    /* QK^T (swapped): S'[j][q], log2 domain */                                     \
    f32x4 st0 = {0,0,0,0}, st1 = {0,0,0,0};                                         \
    st0 = __builtin_amdgcn_mfma_f32_16x16x32_bf16(fr00, ga0, st0, 0, 0, 0);         \
    st0 = __builtin_amdgcn_mfma_f32_16x16x32_bf16(fr01, ga1, st0, 0, 0, 0);         \
    st1 = __builtin_amdgcn_mfma_f32_16x16x32_bf16(fr10, ga0, st1, 0, 0, 0);         \
    st1 = __builtin_amdgcn_mfma_f32_16x16x32_bf16(fr11, ga1, st1, 0, 0, 0);         \
    /* prefetch f(it+1) */                                                          \
    const int jn = ((IT) < 63) ? jb + 1 : jb;                                       \
    const unsigned short* fnp = fMb + (size_t)(jn * 32 + l15) * 64 + 8 * sub;       \
    const s16x8 fn00 = *(const s16x8*)(fnp);                                        \
    const s16x8 fn01 = *(const s16x8*)(fnp + 32);                                   \
    const s16x8 fn10 = *(const s16x8*)(fnp + 1024);                                 \
    const s16x8 fn11 = *(const s16x8*)(fnp + 1024 + 32);                            \
    /* online softmax; defer-max THR=8 */                                           \
    float tmx = fmaxf(fmaxf(fmaxf(st0[0], st0[1]), fmaxf(st0[2], st0[3])),          \
                      fmaxf(fmaxf(st1[0], st1[1]), fmaxf(st1[2], st1[3])));         \
    tmx = fmaxf(tmx, __shfl_xor(tmx, 16));                                          \
    tmx = fmaxf(tmx, __shfl_xor(tmx, 32));                                          \
    float sc = 1.0f;                                                                \
    if (__any(tmx > mrun + 8.0f)) {                                                 \
      const float mn = fmaxf(mrun, tmx);                                            \
      sc = __builtin_amdgcn_exp2f(mrun - mn);                                       \
      mrun = mn; lsum *= sc;                                                        \
    }                                                                               \
    float p0[4], p1[4];                                                             \
    _Pragma("unroll")                                                               \
    for (int v = 0; v < 4; ++v) {                                                   \
      p0[v] = __builtin_amdgcn_exp2f(st0[v] - mrun);                                \
      p1[v] = __builtin_amdgcn_exp2f(st1[v] - mrun);                                \
    }                                                                               \
    float rs = (p0[0] + p0[1]) + (p0[2] + p0[3]) + (p1[0] + p1[1]) + (p1[2] + p1[3]);\
    rs += __shfl_xor(rs, 16);                                                       \
    rs += __shfl_xor(rs, 32);                                                       \
    lsum += rs;                                                                     \
    const unsigned pk0 = cvt_pk_bf16(p0[0], p0[1]);                                 \
    const unsigned pk1 = cvt_pk_bf16(p0[2], p0[3]);                                 \
    const unsigned pk2 = cvt_pk_bf16(p1[0], p1[1]);                                 \
    const unsigned pk3 = cvt_pk_bf16(p1[2], p1[3]);                                 \
    unsigned* pbp = pbS + (PAR) * 1280;                                             \
    *(u32x2*)&pbp[qown * 20 + 2 * sub]     = (u32x2){pk0, pk1};                     \
    *(u32x2*)&pbp[qown * 20 + 8 + 2 * sub] = (u32x2){pk2, pk3};                     \
    if (sub == 0) scS[(PAR) * 64 + qown] = sc;                                      \
    /* issue h(it+1) into HNXT: full-iteration latency cover */                     \
    {                                                                               \
      const unsigned short* hp = hlane + (size_t)jn * 16384;                        \
      _Pragma("unroll")                                                             \
      for (int ct = 0; ct < 8; ++ct) HNXT[ct] = *(const s16x8*)(hp + ct * 512);     \
    }                                                                               \
    __syncthreads();                                                                \
    /* PV: rescale (rare) + 8 c-tiles x 4 q-tiles on HCUR */                        \
    float sc4[4];                                                                   \
    _Pragma("unroll")                                                               \
    for (int qt = 0; qt < 4; ++qt) sc4[qt] = scS[(PAR) * 64 + qt * 16 + l15];       \
    if (__any(fminf(fminf(sc4[0], sc4[1]), fminf(sc4[2], sc4[3])) < 1.0f)) {        \
      _Pragma("unroll")                                                             \
      for (int ct = 0; ct < 8; ++ct)                                                \
        _Pragma("unroll")                                                           \
        for (int qt = 0; qt < 4; ++qt) o[ct][qt] *= sc4[qt];                        \
    }                                                                               \
    s16x8 pa[4];                                                                    \
    _Pragma("unroll")                                                               \
    for (int qt = 0; qt < 4; ++qt)                                                  \
      pa[qt] = *(const s16x8*)((const unsigned short*)pbp + (qt * 16 + l15) * 40 + sub * 8);\
    __builtin_amdgcn_s_setprio(1);                                                  \
    _Pragma("unroll")                                                               \
    for (int qt = 0; qt < 4; ++qt) {                                                \
      _Pragma("unroll")                                                             \
      for (int ct = 0; ct < 8; ++ct)                                                \
        o[ct][qt] = __builtin_amdgcn_mfma_f32_16x16x32_bf16(HCUR[ct], pa[qt], o[ct][qt], 0, 0, 0);\
    }                                                                               \
    __builtin_amdgcn_s_setprio(0);                                                  \
    fr00 = fn00; fr01 = fn01; fr10 = fn10; fr11 = fn11;                             \
  }

  for (int itp = 0; itp < 32; ++itp) {
    ATTN_BODY(itp * 2,     hA, hB, 0)
    ATTN_BODY(itp * 2 + 1, hB, hA, 1)
  }
#undef ATTN_BODY

  // ---- merge the two streams + epilogue
  if (sub == 0) { mfin[s][qown] = mrun; lfin[s][qown] = lsum; }
  __syncthreads();
  const float gam = gamma[0];
  float* oldsS = (float*)(smem + s * 33024);   // per-stream [16][516] f32
  const float* oA = (const float*)smem;
  const float* oB = (const float*)(smem + 33024);
#pragma unroll
  for (int qt = 0; qt < 4; ++qt) {
    const int q = qt * 16 + l15;
    const float mA = mfin[0][q], mB = mfin[1][q];
    const float mm = fmaxf(mA, mB);
    const float eA = __builtin_amdgcn_exp2f(mA - mm);
    const float eB = __builtin_amdgcn_exp2f(mB - mm);
    const float Lt = lfin[0][q] * eA + lfin[1][q] * eB;
    const float fac = gam * ((s == 0) ? eA : eB) / Lt;
#pragma unroll
    for (int ct = 0; ct < 8; ++ct) {
      const f32x4 vv = o[ct][qt] * fac;
      *(f32x4*)&oldsS[l15 * 516 + ws * 128 + ct * 16 + 4 * sub] = vv;
    }
    __syncthreads();
    const int r = tid >> 5, c0 = (tid & 31) * 16;
    const float* xr  = x   + ((size_t)b * 4096 + qbase + qt * 16 + r) * 512;
    float*       orw = out + ((size_t)b * 4096 + qbase + qt * 16 + r) * 512;
#pragma unroll
    for (int i = 0; i < 4; ++i) {
      const int cc = c0 + i * 4;
      const f32x4 va = *(const f32x4*)&oA[r * 516 + cc];
      const f32x4 vb = *(const f32x4*)&oB[r * 516 + cc];
      const f32x4 xv = *(const f32x4*)(xr + cc);
      *(f32x4*)(orw + cc) = va + vb + xv;
    }
    __syncthreads();
  }
}

extern "C" void kernel_launch(void* const* d_in, const int* in_sizes, int n_in,
                              void* d_out, int out_size, void* d_ws, size_t ws_size,
                              hipStream_t stream) {
  const float* x     = (const float*)d_in[0];
  const float* kf    = (const float*)d_in[1];
  const float* kg    = (const float*)d_in[2];
  const float* kh    = (const float*)d_in[3];
  const float* bf    = (const float*)d_in[4];
  const float* bg    = (const float*)d_in[5];
  const float* bh    = (const float*)d_in[6];
  const float* gamma = (const float*)d_in[7];
  float* out = (float*)d_out;

  char* ws = (char*)d_ws;
  unsigned short* fO = (unsigned short*)(ws);
  unsigned short* gO = (unsigned short*)(ws + (2u << 20));
  unsigned short* hP = (unsigned short*)(ws + (4u << 20));
  unsigned short* wT = (unsigned short*)(ws + (20u << 20));

  hipLaunchKernelGGL(wt_kernel,   dim3(10, 4),  dim3(256), 0, stream, kf, kg, kh, wT);
  hipLaunchKernelGGL(gemm_kernel, dim3(256, 2), dim3(256), 0, stream,
                     x, wT, bf, bg, bh, fO, gO, hP);
  hipLaunchKernelGGL(attn_kernel, dim3(256),    dim3(512), 0, stream,
                     fO, gO, hP, x, gamma, out);
}